// Round 1
// baseline (117.174 us; speedup 1.0000x reference)
//
#include <hip/hip_runtime.h>
#include <math.h>

// Problem constants (from reference)
#define B 8
#define T 512
#define D 256
#define S 64
#define P 1024
#define R 12

// -----------------------------------------------------------------------------
// Kernel 1: ragged span max-pool + per-span linear precompute.
// grid = B*S blocks, 256 threads (one per d).
// Outputs:
//   sp[b*S+s][d]      = max over t in [start, start+len] of encoded[b,t,d]
//   lin[b*S+s][o]     o<12: sum_d sp[d]*Wl[d][o]      (head-side linear)
//                     o>=12: sum_d sp[d]*Wl[D+d][o-12] (tail-side linear)
// -----------------------------------------------------------------------------
__global__ __launch_bounds__(256) void k_span_pool(
    const float* __restrict__ enc, const int* __restrict__ starts,
    const int* __restrict__ lens, const float* __restrict__ Wl,
    float* __restrict__ sp, float* __restrict__ lin)
{
    int bs = blockIdx.x;          // b*S + s
    int b  = bs >> 6;             // S = 64
    int d  = threadIdx.x;
    int st = starts[bs];
    int ln = lens[bs];            // end = st + ln + 1 (inclusive of st+ln)

    const float* base = enc + ((size_t)(b * T + st)) * D + d;
    float m = base[0];
    for (int i = 1; i <= ln; ++i) m = fmaxf(m, base[(size_t)i * D]);
    sp[(size_t)bs * D + d] = m;

    __shared__ float smem[256];
    smem[d] = m;
    __syncthreads();

    // 24 linear outputs; 4 waves x 6 outputs each, 64-lane shuffle reduce
    int wave = d >> 6, lane = d & 63;
    #pragma unroll
    for (int oo = 0; oo < 6; ++oo) {
        int o = wave * 6 + oo;                 // 0..23
        int r = (o < 12) ? o : (o - 12);
        int rowbase = (o < 12) ? 0 : D;
        float p = 0.f;
        #pragma unroll
        for (int k = 0; k < 4; ++k) {
            int dd = lane + 64 * k;
            p = fmaf(smem[dd], Wl[(size_t)(rowbase + dd) * R + r], p);
        }
        #pragma unroll
        for (int off = 32; off > 0; off >>= 1) p += __shfl_down(p, off, 64);
        if (lane == 0) lin[(size_t)bs * 24 + o] = p;
    }
}

// -----------------------------------------------------------------------------
// Kernel 2: U[row][r][e] = sum_d sp[row][d] * Wb[r][d][e]
// 12 independent 512x256x256 f32 GEMMs on the vector ALU (no f32 MFMA).
// grid = (32 row-tiles, 12 r), 256 threads (one per e), TM=16 rows/block.
// 16 FMA per global W load; sp tile broadcast from LDS (conflict-free).
// -----------------------------------------------------------------------------
#define TM 16
__global__ __launch_bounds__(256) void k_bilinear_U(
    const float* __restrict__ sp, const float* __restrict__ Wb,
    float* __restrict__ U)
{
    int mt  = blockIdx.x;         // row tile 0..31
    int r   = blockIdx.y;         // 0..11
    int tid = threadIdx.x;        // e = tid

    __shared__ float a[TM][256];  // 16 KB
    int row0 = mt * TM;
    #pragma unroll
    for (int j = 0; j < TM; ++j)
        a[j][tid] = sp[(size_t)(row0 + j) * D + tid];
    __syncthreads();

    float acc[TM];
    #pragma unroll
    for (int j = 0; j < TM; ++j) acc[j] = 0.f;

    const float* w = Wb + (size_t)r * D * D + tid;
    for (int d = 0; d < D; d += 4) {
        float w0 = w[(size_t)(d + 0) * D];
        float w1 = w[(size_t)(d + 1) * D];
        float w2 = w[(size_t)(d + 2) * D];
        float w3 = w[(size_t)(d + 3) * D];
        #pragma unroll
        for (int j = 0; j < TM; ++j) {
            float4 av = *(const float4*)&a[j][d];
            acc[j] = fmaf(av.x, w0, acc[j]);
            acc[j] = fmaf(av.y, w1, acc[j]);
            acc[j] = fmaf(av.z, w2, acc[j]);
            acc[j] = fmaf(av.w, w3, acc[j]);
        }
    }

    #pragma unroll
    for (int j = 0; j < TM; ++j)
        U[((size_t)(row0 + j) * R + r) * D + tid] = acc[j];
}

// -----------------------------------------------------------------------------
// Kernel 3: per-pair scores.
// score[b,p,r] = sigmoid( b_lin[r] + linH[b,h,r] + linT[b,t,r]
//                         + sum_e U[b,h,r,e] * sp[b,t,e] )
// One 64-lane wave per pair, 4 waves per block. grid = B*P/4 = 2048.
// -----------------------------------------------------------------------------
__global__ __launch_bounds__(256) void k_scores(
    const float* __restrict__ sp, const float* __restrict__ U,
    const float* __restrict__ lin, const int* __restrict__ ph,
    const int* __restrict__ pt, const float* __restrict__ bl,
    float* __restrict__ out)
{
    int pair = blockIdx.x * 4 + (threadIdx.x >> 6);
    int lane = threadIdx.x & 63;
    int b = pair >> 10;           // P = 1024
    int p = pair & 1023;

    int h = ph[(size_t)b * P + p];
    int t = pt[(size_t)b * P + p];

    const float* tailp = sp + ((size_t)(b * S + t)) * D;
    float tv[4];
    #pragma unroll
    for (int k = 0; k < 4; ++k) tv[k] = tailp[lane + 64 * k];

    const float* Ub   = U   + ((size_t)(b * S + h)) * R * D;
    const float* linH = lin + ((size_t)(b * S + h)) * 24;
    const float* linT = lin + ((size_t)(b * S + t)) * 24;

    #pragma unroll 1
    for (int r = 0; r < R; ++r) {
        const float* ur = Ub + (size_t)r * D;
        float acc = 0.f;
        #pragma unroll
        for (int k = 0; k < 4; ++k) acc = fmaf(ur[lane + 64 * k], tv[k], acc);
        #pragma unroll
        for (int off = 32; off > 0; off >>= 1) acc += __shfl_down(acc, off, 64);
        if (lane == 0) {
            float sc = acc + linH[r] + linT[12 + r] + bl[r];
            out[(size_t)(b * P + p) * R + r] = 1.f / (1.f + expf(-sc));
        }
    }
}

// -----------------------------------------------------------------------------
extern "C" void kernel_launch(void* const* d_in, const int* in_sizes, int n_in,
                              void* d_out, int out_size, void* d_ws, size_t ws_size,
                              hipStream_t stream) {
    const float* enc    = (const float*)d_in[0];   // [B,T,D]
    const float* Wl     = (const float*)d_in[1];   // [2D,R]
    const float* bl     = (const float*)d_in[2];   // [R]
    const float* Wb     = (const float*)d_in[3];   // [R,D,D]
    const int*   starts = (const int*)d_in[4];     // [B,S]
    const int*   lens   = (const int*)d_in[5];     // [B,S]
    const int*   ph     = (const int*)d_in[6];     // [B,P]
    const int*   pt     = (const int*)d_in[7];     // [B,P]
    float* out = (float*)d_out;                    // [B,P,R]

    // workspace layout (floats): sp [B*S*D] | U [B*S*R*D] | lin [B*S*24]
    float* sp  = (float*)d_ws;
    float* U   = sp + (size_t)B * S * D;
    float* lin = U + (size_t)B * S * R * D;

    k_span_pool <<<B * S,        256, 0, stream>>>(enc, starts, lens, Wl, sp, lin);
    k_bilinear_U<<<dim3(32, R),  256, 0, stream>>>(sp, Wb, U);
    k_scores    <<<B * P / 4,    256, 0, stream>>>(sp, U, lin, ph, pt, bl, out);
}

// Round 2
// 101.023 us; speedup vs baseline: 1.1599x; 1.1599x over previous
//
#include <hip/hip_runtime.h>
#include <math.h>

// Problem constants (from reference)
#define B 8
#define T 512
#define D 256
#define S 64
#define P 1024
#define R 12

typedef __attribute__((ext_vector_type(8)))  short bf16x8;   // 8 bf16 = 4 VGPRs
typedef __attribute__((ext_vector_type(16))) float f32x16;   // MFMA 32x32 accum

static __device__ inline short f2bf(float f) {
    union { float f; unsigned u; } v; v.f = f;
    unsigned u = v.u + 0x7fff + ((v.u >> 16) & 1);   // RNE
    return (short)(u >> 16);
}

// -----------------------------------------------------------------------------
// Kernel 1: ragged span max-pool + per-span linear precompute + bf16 copy.
// grid = B*S blocks, 256 threads (one per d).
// -----------------------------------------------------------------------------
__global__ __launch_bounds__(256) void k_span_pool(
    const float* __restrict__ enc, const int* __restrict__ starts,
    const int* __restrict__ lens, const float* __restrict__ Wl,
    float* __restrict__ sp, short* __restrict__ spb, float* __restrict__ lin)
{
    int bs = blockIdx.x;          // b*S + s
    int b  = bs >> 6;             // S = 64
    int d  = threadIdx.x;
    int st = starts[bs];
    int ln = lens[bs];            // inclusive end = st + ln

    const float* base = enc + ((size_t)(b * T + st)) * D + d;
    float m = base[0];
    for (int i = 1; i <= ln; ++i) m = fmaxf(m, base[(size_t)i * D]);
    sp [(size_t)bs * D + d] = m;
    spb[(size_t)bs * D + d] = f2bf(m);

    __shared__ float smem[256];
    smem[d] = m;
    __syncthreads();

    // 24 linear outputs; 4 waves x 6 outputs each, 64-lane shuffle reduce
    int wave = d >> 6, lane = d & 63;
    #pragma unroll
    for (int oo = 0; oo < 6; ++oo) {
        int o = wave * 6 + oo;                 // 0..23
        int r = (o < 12) ? o : (o - 12);
        int rowbase = (o < 12) ? 0 : D;
        float p = 0.f;
        #pragma unroll
        for (int k = 0; k < 4; ++k) {
            int dd = lane + 64 * k;
            p = fmaf(smem[dd], Wl[(size_t)(rowbase + dd) * R + r], p);
        }
        #pragma unroll
        for (int off = 32; off > 0; off >>= 1) p += __shfl_down(p, off, 64);
        if (lane == 0) lin[(size_t)bs * 24 + o] = p;
    }
}

// -----------------------------------------------------------------------------
// Kernel 2: transpose+convert Wb[r][d][e] (f32) -> Wt[r][e][d] (bf16).
// grid = (32 dblk, 12 r), 256 threads (one per e). Loads coalesced across e,
// store = one 16B short8 per thread.
// -----------------------------------------------------------------------------
__global__ __launch_bounds__(256) void k_wb_transpose(
    const float* __restrict__ Wb, short* __restrict__ Wt)
{
    int dblk = blockIdx.x;        // 0..31, covers d = dblk*8 .. +8
    int r    = blockIdx.y;        // 0..11
    int e    = threadIdx.x;       // 0..255

    const float* src = Wb + ((size_t)r * D + dblk * 8) * D + e;
    short v[8];
    #pragma unroll
    for (int j = 0; j < 8; ++j) v[j] = f2bf(src[(size_t)j * D]);

    short* dst = Wt + ((size_t)r * D + e) * D + dblk * 8;
    *(bf16x8*)dst = *(bf16x8*)v;
}

// -----------------------------------------------------------------------------
// Kernel 3: U[row][r][e] = sum_d sp[row][d] * Wb[r][d][e]  via bf16 MFMA.
// 12 GEMMs M=512 N=256 K=256. Block = 4 waves, each wave one 32x32 tile,
// block tile 64x64. Fragments loaded straight from global (no LDS).
//   A[m][k] layout: lane reads spb[m0+(lane&31)][kc+(lane>>5)*8 ..+8]
//   B[k][n] via Wt[r][n][d]: lane reads Wt[r][n0+(lane&31)][kc+(lane>>5)*8..]
//   C/D: n = lane&31, m = (reg&3) + 8*(reg>>2) + 4*(lane>>5)   [guide §3]
// -----------------------------------------------------------------------------
__global__ __launch_bounds__(256) void k_bilinear_mfma(
    const short* __restrict__ spb, const short* __restrict__ Wt,
    float* __restrict__ U)
{
    int wave = threadIdx.x >> 6;
    int lane = threadIdx.x & 63;
    int m0 = blockIdx.x * 64 + (wave >> 1) * 32;
    int n0 = blockIdx.y * 64 + (wave & 1) * 32;
    int r  = blockIdx.z;

    int half = lane >> 5;         // 0/1: which k-octet
    int mn   = lane & 31;

    const short* ap = spb + (size_t)(m0 + mn) * D + half * 8;
    const short* bp = Wt + ((size_t)r * D + (n0 + mn)) * D + half * 8;

    f32x16 acc = {};
    #pragma unroll
    for (int ks = 0; ks < 16; ++ks) {
        bf16x8 a = *(const bf16x8*)(ap + ks * 16);
        bf16x8 b = *(const bf16x8*)(bp + ks * 16);
        acc = __builtin_amdgcn_mfma_f32_32x32x16_bf16(a, b, acc, 0, 0, 0);
    }

    #pragma unroll
    for (int reg = 0; reg < 16; ++reg) {
        int m = m0 + (reg & 3) + 8 * (reg >> 2) + 4 * half;
        int n = n0 + mn;
        U[((size_t)m * R + r) * D + n] = acc[reg];
    }
}

// -----------------------------------------------------------------------------
// Kernel 4: per-pair scores. One wave per pair, float4 loads, 12 independent
// accumulators so the shuffle-reduce chains pipeline.
// -----------------------------------------------------------------------------
__global__ __launch_bounds__(256) void k_scores(
    const float* __restrict__ sp, const float* __restrict__ U,
    const float* __restrict__ lin, const int* __restrict__ ph,
    const int* __restrict__ pt, const float* __restrict__ bl,
    float* __restrict__ out)
{
    int pair = blockIdx.x * 4 + (threadIdx.x >> 6);
    int lane = threadIdx.x & 63;
    int b = pair >> 10;           // P = 1024
    int p = pair & 1023;

    int h = ph[(size_t)b * P + p];
    int t = pt[(size_t)b * P + p];

    float4 tv = ((const float4*)(sp + ((size_t)(b * S + t)) * D))[lane];
    const float4* Up = (const float4*)(U + ((size_t)(b * S + h)) * R * D);

    float acc[R];
    #pragma unroll
    for (int r = 0; r < R; ++r) {
        float4 u = Up[r * 64 + lane];
        float a = u.x * tv.x;
        a = fmaf(u.y, tv.y, a);
        a = fmaf(u.z, tv.z, a);
        a = fmaf(u.w, tv.w, a);
        acc[r] = a;
    }
    #pragma unroll
    for (int off = 32; off > 0; off >>= 1) {
        #pragma unroll
        for (int r = 0; r < R; ++r) acc[r] += __shfl_down(acc[r], off, 64);
    }

    if (lane == 0) {
        const float* linH = lin + ((size_t)(b * S + h)) * 24;
        const float* linT = lin + ((size_t)(b * S + t)) * 24;
        #pragma unroll
        for (int r = 0; r < R; ++r) {
            float sc = acc[r] + linH[r] + linT[12 + r] + bl[r];
            out[(size_t)(b * P + p) * R + r] = 1.f / (1.f + expf(-sc));
        }
    }
}

// -----------------------------------------------------------------------------
extern "C" void kernel_launch(void* const* d_in, const int* in_sizes, int n_in,
                              void* d_out, int out_size, void* d_ws, size_t ws_size,
                              hipStream_t stream) {
    const float* enc    = (const float*)d_in[0];   // [B,T,D]
    const float* Wl     = (const float*)d_in[1];   // [2D,R]
    const float* bl     = (const float*)d_in[2];   // [R]
    const float* Wb     = (const float*)d_in[3];   // [R,D,D]
    const int*   starts = (const int*)d_in[4];     // [B,S]
    const int*   lens   = (const int*)d_in[5];     // [B,S]
    const int*   ph     = (const int*)d_in[6];     // [B,P]
    const int*   pt     = (const int*)d_in[7];     // [B,P]
    float* out = (float*)d_out;                    // [B,P,R]

    // workspace layout: sp f32 [512*256] | U f32 [512*12*256] | lin f32 [512*24]
    //                   | spb bf16 [512*256] | Wt bf16 [12*256*256]
    float* sp  = (float*)d_ws;
    float* U   = sp + (size_t)B * S * D;
    float* lin = U + (size_t)B * S * R * D;
    short* spb = (short*)(lin + (size_t)B * S * 24);
    short* Wt  = spb + (size_t)B * S * D;

    k_span_pool    <<<B * S,              256, 0, stream>>>(enc, starts, lens, Wl, sp, spb, lin);
    k_wb_transpose <<<dim3(32, R),        256, 0, stream>>>(Wb, Wt);
    k_bilinear_mfma<<<dim3(8, 4, R),      256, 0, stream>>>(spb, Wt, U);
    k_scores       <<<B * P / 4,          256, 0, stream>>>(sp, U, lin, ph, pt, bl, out);
}

// Round 3
// 97.030 us; speedup vs baseline: 1.2076x; 1.0412x over previous
//
#include <hip/hip_runtime.h>
#include <math.h>

// Problem constants (from reference)
#define B 8
#define T 512
#define D 256
#define S 64
#define P 1024
#define R 12

typedef __attribute__((ext_vector_type(8)))  short bf16x8;   // 8 bf16 = 4 VGPRs
typedef __attribute__((ext_vector_type(16))) float f32x16;   // MFMA 32x32 accum

static __device__ inline short f2bf(float f) {
    union { float f; unsigned u; } v; v.f = f;
    unsigned u = v.u + 0x7fff + ((v.u >> 16) & 1);   // RNE
    return (short)(u >> 16);
}
static __device__ inline float bf2f(unsigned short h) {
    union { unsigned u; float f; } v; v.u = ((unsigned)h) << 16;
    return v.f;
}

// -----------------------------------------------------------------------------
// Kernel A (merged): blocks [0,512): ragged span max-pool + per-span linear
// precompute + bf16 copy. blocks [512,896): Wb[r][d][e] f32 -> Wt[r][e][d] bf16.
// -----------------------------------------------------------------------------
__global__ __launch_bounds__(256) void k_prep(
    const float* __restrict__ enc, const int* __restrict__ starts,
    const int* __restrict__ lens, const float* __restrict__ Wl,
    const float* __restrict__ Wb,
    float* __restrict__ sp, short* __restrict__ spb, float* __restrict__ lin,
    short* __restrict__ Wt)
{
    if (blockIdx.x < B * S) {
        // ---- span max-pool ----
        int bs = blockIdx.x;          // b*S + s
        int b  = bs >> 6;             // S = 64
        int d  = threadIdx.x;
        int st = starts[bs];
        int ln = lens[bs];            // inclusive last offset; ln in [0,11]

        const float* base = enc + ((size_t)(b * T + st)) * D + d;
        float m = base[0];
        // clamped full unroll: 11 independent loads, no serial latency chain
        #pragma unroll
        for (int i = 1; i < 12; ++i) {
            int idx = (i <= ln) ? i : ln;
            m = fmaxf(m, base[(size_t)idx * D]);
        }
        sp [(size_t)bs * D + d] = m;
        spb[(size_t)bs * D + d] = f2bf(m);

        __shared__ float smem[256];
        smem[d] = m;
        __syncthreads();

        // 24 linear outputs; 4 waves x 6 outputs each, 64-lane shuffle reduce
        int wave = d >> 6, lane = d & 63;
        #pragma unroll
        for (int oo = 0; oo < 6; ++oo) {
            int o = wave * 6 + oo;                 // 0..23
            int r = (o < 12) ? o : (o - 12);
            int rowbase = (o < 12) ? 0 : D;
            float p = 0.f;
            #pragma unroll
            for (int k = 0; k < 4; ++k) {
                int dd = lane + 64 * k;
                p = fmaf(smem[dd], Wl[(size_t)(rowbase + dd) * R + r], p);
            }
            #pragma unroll
            for (int off = 32; off > 0; off >>= 1) p += __shfl_down(p, off, 64);
            if (lane == 0) lin[(size_t)bs * 24 + o] = p;
        }
    } else {
        // ---- Wb transpose + bf16 convert ----
        int bid  = blockIdx.x - B * S;  // 0..383
        int dblk = bid & 31;            // d block (8 rows)
        int r    = bid >> 5;            // 0..11
        int e    = threadIdx.x;         // 0..255

        const float* src = Wb + ((size_t)r * D + dblk * 8) * D + e;
        short v[8];
        #pragma unroll
        for (int j = 0; j < 8; ++j) v[j] = f2bf(src[(size_t)j * D]);

        short* dst = Wt + ((size_t)r * D + e) * D + dblk * 8;
        *(bf16x8*)dst = *(bf16x8*)v;
    }
}

// -----------------------------------------------------------------------------
// Kernel B: U[row][r][e] = sum_d sp[row][d] * Wb[r][d][e]  via bf16 MFMA.
// 12 GEMMs M=512 N=256 K=256. Block = 4 waves, each wave one 32x32 tile,
// block tile 64x64. Fragments loaded straight from global (no LDS).
// Output stored as bf16 (halves k_scores' read traffic).
// -----------------------------------------------------------------------------
__global__ __launch_bounds__(256) void k_bilinear_mfma(
    const short* __restrict__ spb, const short* __restrict__ Wt,
    short* __restrict__ U)
{
    int wave = threadIdx.x >> 6;
    int lane = threadIdx.x & 63;
    int m0 = blockIdx.x * 64 + (wave >> 1) * 32;
    int n0 = blockIdx.y * 64 + (wave & 1) * 32;
    int r  = blockIdx.z;

    int half = lane >> 5;         // 0/1: which k-octet
    int mn   = lane & 31;

    const short* ap = spb + (size_t)(m0 + mn) * D + half * 8;
    const short* bp = Wt + ((size_t)r * D + (n0 + mn)) * D + half * 8;

    f32x16 acc = {};
    #pragma unroll
    for (int ks = 0; ks < 16; ++ks) {
        bf16x8 a = *(const bf16x8*)(ap + ks * 16);
        bf16x8 b = *(const bf16x8*)(bp + ks * 16);
        acc = __builtin_amdgcn_mfma_f32_32x32x16_bf16(a, b, acc, 0, 0, 0);
    }

    #pragma unroll
    for (int reg = 0; reg < 16; ++reg) {
        int m = m0 + (reg & 3) + 8 * (reg >> 2) + 4 * half;
        int n = n0 + mn;
        U[((size_t)m * R + r) * D + n] = f2bf(acc[reg]);
    }
}

// -----------------------------------------------------------------------------
// Kernel C: per-pair scores. One wave per pair; U read as bf16 (ushort4/lane),
// tail as float4/lane; 12 independent accumulators so reduces pipeline.
// -----------------------------------------------------------------------------
__global__ __launch_bounds__(256) void k_scores(
    const float* __restrict__ sp, const short* __restrict__ U,
    const float* __restrict__ lin, const int* __restrict__ ph,
    const int* __restrict__ pt, const float* __restrict__ bl,
    float* __restrict__ out)
{
    int pair = blockIdx.x * 4 + (threadIdx.x >> 6);
    int lane = threadIdx.x & 63;
    int b = pair >> 10;           // P = 1024
    int p = pair & 1023;

    int h = ph[(size_t)b * P + p];
    int t = pt[(size_t)b * P + p];

    float4 tv = ((const float4*)(sp + ((size_t)(b * S + t)) * D))[lane];
    const ushort4* Up = (const ushort4*)(U + ((size_t)(b * S + h)) * R * D);

    float acc[R];
    #pragma unroll
    for (int r = 0; r < R; ++r) {
        ushort4 u = Up[r * 64 + lane];
        float a = bf2f(u.x) * tv.x;
        a = fmaf(bf2f(u.y), tv.y, a);
        a = fmaf(bf2f(u.z), tv.z, a);
        a = fmaf(bf2f(u.w), tv.w, a);
        acc[r] = a;
    }
    #pragma unroll
    for (int off = 32; off > 0; off >>= 1) {
        #pragma unroll
        for (int r = 0; r < R; ++r) acc[r] += __shfl_down(acc[r], off, 64);
    }

    if (lane == 0) {
        const float* linH = lin + ((size_t)(b * S + h)) * 24;
        const float* linT = lin + ((size_t)(b * S + t)) * 24;
        float s[R];
        #pragma unroll
        for (int r = 0; r < R; ++r) {
            float sc = acc[r] + linH[r] + linT[12 + r] + bl[r];
            s[r] = 1.f / (1.f + expf(-sc));
        }
        float4* op = (float4*)(out + (size_t)(b * P + p) * R);
        op[0] = make_float4(s[0], s[1], s[2],  s[3]);
        op[1] = make_float4(s[4], s[5], s[6],  s[7]);
        op[2] = make_float4(s[8], s[9], s[10], s[11]);
    }
}

// -----------------------------------------------------------------------------
extern "C" void kernel_launch(void* const* d_in, const int* in_sizes, int n_in,
                              void* d_out, int out_size, void* d_ws, size_t ws_size,
                              hipStream_t stream) {
    const float* enc    = (const float*)d_in[0];   // [B,T,D]
    const float* Wl     = (const float*)d_in[1];   // [2D,R]
    const float* bl     = (const float*)d_in[2];   // [R]
    const float* Wb     = (const float*)d_in[3];   // [R,D,D]
    const int*   starts = (const int*)d_in[4];     // [B,S]
    const int*   lens   = (const int*)d_in[5];     // [B,S]
    const int*   ph     = (const int*)d_in[6];     // [B,P]
    const int*   pt     = (const int*)d_in[7];     // [B,P]
    float* out = (float*)d_out;                    // [B,P,R]

    // workspace (all 16B-aligned segments):
    //   sp  f32  [512*256]      = 512 KB
    //   lin f32  [512*24]       =  48 KB
    //   spb bf16 [512*256]      = 256 KB
    //   U   bf16 [512*12*256]   =   3 MB
    //   Wt  bf16 [12*256*256]   = 1.5 MB
    float* sp  = (float*)d_ws;
    float* lin = sp + (size_t)B * S * D;
    short* spb = (short*)(lin + (size_t)B * S * 24);
    short* U   = spb + (size_t)B * S * D;
    short* Wt  = U + (size_t)B * S * R * D;

    k_prep         <<<B * S + 32 * R, 256, 0, stream>>>(enc, starts, lens, Wl, Wb, sp, spb, lin, Wt);
    k_bilinear_mfma<<<dim3(8, 4, R),  256, 0, stream>>>(spb, Wt, U);
    k_scores       <<<B * P / 4,      256, 0, stream>>>(sp, U, lin, ph, pt, bl, out);
}

// Round 4
// 91.299 us; speedup vs baseline: 1.2834x; 1.0628x over previous
//
#include <hip/hip_runtime.h>
#include <math.h>

// Problem constants (from reference)
#define B 8
#define T 512
#define D 256
#define S 64
#define P 1024
#define R 12

typedef __attribute__((ext_vector_type(8)))  short bf16x8;   // 8 bf16 = 4 VGPRs
typedef __attribute__((ext_vector_type(16))) float f32x16;   // MFMA 32x32 accum

static __device__ inline short f2bf(float f) {
    union { float f; unsigned u; } v; v.f = f;
    unsigned u = v.u + 0x7fff + ((v.u >> 16) & 1);   // RNE
    return (short)(u >> 16);
}

// -----------------------------------------------------------------------------
// Kernel A (merged): blocks [0,512): ragged span max-pool + per-span linear
// precompute + bf16 span vectors. blocks [512,896): Wb[r][d][e] -> Wt[r][e][d] bf16.
// -----------------------------------------------------------------------------
__global__ __launch_bounds__(256) void k_prep(
    const float* __restrict__ enc, const int* __restrict__ starts,
    const int* __restrict__ lens, const float* __restrict__ Wl,
    const float* __restrict__ Wb,
    short* __restrict__ spb, float* __restrict__ lin, short* __restrict__ Wt)
{
    if (blockIdx.x < B * S) {
        // ---- span max-pool ----
        int bs = blockIdx.x;          // b*S + s
        int b  = bs >> 6;             // S = 64
        int d  = threadIdx.x;
        int st = starts[bs];
        int ln = lens[bs];            // inclusive last offset; ln in [0,11]

        const float* base = enc + ((size_t)(b * T + st)) * D + d;
        float m = base[0];
        // clamped full unroll: independent loads, no serial latency chain
        #pragma unroll
        for (int i = 1; i < 12; ++i) {
            int idx = (i <= ln) ? i : ln;
            m = fmaxf(m, base[(size_t)idx * D]);
        }
        spb[(size_t)bs * D + d] = f2bf(m);

        __shared__ float smem[256];
        smem[d] = m;
        __syncthreads();

        // 24 linear outputs; 4 waves x 6 outputs each, 64-lane shuffle reduce
        int wave = d >> 6, lane = d & 63;
        #pragma unroll
        for (int oo = 0; oo < 6; ++oo) {
            int o = wave * 6 + oo;                 // 0..23
            int r = (o < 12) ? o : (o - 12);
            int rowbase = (o < 12) ? 0 : D;
            float p = 0.f;
            #pragma unroll
            for (int k = 0; k < 4; ++k) {
                int dd = lane + 64 * k;
                p = fmaf(smem[dd], Wl[(size_t)(rowbase + dd) * R + r], p);
            }
            #pragma unroll
            for (int off = 32; off > 0; off >>= 1) p += __shfl_down(p, off, 64);
            if (lane == 0) lin[(size_t)bs * 24 + o] = p;
        }
    } else {
        // ---- Wb transpose + bf16 convert ----
        int bid  = blockIdx.x - B * S;  // 0..383
        int dblk = bid & 31;            // d block (8 rows)
        int r    = bid >> 5;            // 0..11
        int e    = threadIdx.x;         // 0..255

        const float* src = Wb + ((size_t)r * D + dblk * 8) * D + e;
        short v[8];
        #pragma unroll
        for (int j = 0; j < 8; ++j) v[j] = f2bf(src[(size_t)j * D]);

        short* dst = Wt + ((size_t)r * D + e) * D + dblk * 8;
        *(bf16x8*)dst = *(bf16x8*)v;
    }
}

// -----------------------------------------------------------------------------
// Kernel B: fused bilinear. Block = (b, r), 4 waves.
// Phase 1: U[s,e] = sum_d spb[b,s,d] * Wt[r,e,d]   (64 x 256, K=256, MFMA)
//          wave w owns e-quarter w: 2x2 tiles of 32x32. U -> LDS as bf16.
// Phase 2: V[s,t] = sum_e U[s,e] * spb[b,t,e]      (64 x 64,  K=256, MFMA)
//          wave w owns tile (w>>1, w&1). A from LDS, B = spb rows (global).
// Write V[b][s][t][r] f32 — U never touches global memory.
// C/D layout (32x32): n = lane&31, m = (reg&3) + 8*(reg>>2) + 4*(lane>>5).
// -----------------------------------------------------------------------------
#define LDSTRIDE 264   // shorts per U row: 256 + 8 pad (row = 528 B, 16B-aligned)
__global__ __launch_bounds__(256) void k_bilinear_v(
    const short* __restrict__ spb, const short* __restrict__ Wt,
    float* __restrict__ V)
{
    int b = blockIdx.x;
    int r = blockIdx.y;
    int wave = threadIdx.x >> 6;
    int lane = threadIdx.x & 63;
    int half = lane >> 5;         // k-octet selector
    int mn   = lane & 31;

    __shared__ short ldsU[64 * LDSTRIDE];   // ~33 KB

    // ---- phase 1: U = spb[b] * Wt[r]^T ----
    {
        int n0 = wave * 64;       // e-quarter
        const short* ap0 = spb + ((size_t)(b * 64 + mn))      * D + half * 8;
        const short* ap1 = ap0 + 32 * D;
        const short* bp0 = Wt + ((size_t)r * D + (n0 + mn))      * D + half * 8;
        const short* bp1 = bp0 + 32 * D;

        f32x16 acc00 = {}, acc01 = {}, acc10 = {}, acc11 = {};
        #pragma unroll
        for (int ks = 0; ks < 16; ++ks) {
            bf16x8 a0 = *(const bf16x8*)(ap0 + ks * 16);
            bf16x8 a1 = *(const bf16x8*)(ap1 + ks * 16);
            bf16x8 b0 = *(const bf16x8*)(bp0 + ks * 16);
            bf16x8 b1 = *(const bf16x8*)(bp1 + ks * 16);
            acc00 = __builtin_amdgcn_mfma_f32_32x32x16_bf16(a0, b0, acc00, 0, 0, 0);
            acc01 = __builtin_amdgcn_mfma_f32_32x32x16_bf16(a0, b1, acc01, 0, 0, 0);
            acc10 = __builtin_amdgcn_mfma_f32_32x32x16_bf16(a1, b0, acc10, 0, 0, 0);
            acc11 = __builtin_amdgcn_mfma_f32_32x32x16_bf16(a1, b1, acc11, 0, 0, 0);
        }

        #pragma unroll
        for (int reg = 0; reg < 16; ++reg) {
            int mrow = (reg & 3) + 8 * (reg >> 2) + 4 * half;
            int e0 = n0 + mn, e1 = n0 + 32 + mn;
            ldsU[(size_t)(mrow)      * LDSTRIDE + e0] = f2bf(acc00[reg]);
            ldsU[(size_t)(mrow)      * LDSTRIDE + e1] = f2bf(acc01[reg]);
            ldsU[(size_t)(mrow + 32) * LDSTRIDE + e0] = f2bf(acc10[reg]);
            ldsU[(size_t)(mrow + 32) * LDSTRIDE + e1] = f2bf(acc11[reg]);
        }
    }
    __syncthreads();

    // ---- phase 2: V = U * spb[b]^T ----
    {
        int mt = (wave >> 1) * 32;    // s-half
        int nt = (wave & 1) * 32;     // t-half
        const short* ap = ldsU + (size_t)(mt + mn) * LDSTRIDE + half * 8;
        const short* bp = spb + ((size_t)(b * 64 + nt + mn)) * D + half * 8;

        f32x16 acc = {};
        #pragma unroll
        for (int ks = 0; ks < 16; ++ks) {
            bf16x8 a = *(const bf16x8*)(ap + ks * 16);
            bf16x8 bb = *(const bf16x8*)(bp + ks * 16);
            acc = __builtin_amdgcn_mfma_f32_32x32x16_bf16(a, bb, acc, 0, 0, 0);
        }

        #pragma unroll
        for (int reg = 0; reg < 16; ++reg) {
            int s = mt + (reg & 3) + 8 * (reg >> 2) + 4 * half;
            int t = nt + mn;
            V[((size_t)((b * 64 + s) * 64 + t)) * R + r] = acc[reg];
        }
    }
}

// -----------------------------------------------------------------------------
// Kernel C: pure gather + sigmoid. One thread per pair (8192 threads).
// out[b,p,r] = sigmoid(V[b,h,t,r] + linH[r] + linT[12+r] + bl[r])
// -----------------------------------------------------------------------------
__global__ __launch_bounds__(256) void k_gather(
    const float* __restrict__ V, const float* __restrict__ lin,
    const int* __restrict__ ph, const int* __restrict__ pt,
    const float* __restrict__ bl, float* __restrict__ out)
{
    int pair = blockIdx.x * 256 + threadIdx.x;
    int b = pair >> 10;           // P = 1024
    int p = pair & 1023;

    int h = ph[(size_t)b * P + p];
    int t = pt[(size_t)b * P + p];

    const float4* vp = (const float4*)(V + ((size_t)((b * 64 + h) * 64 + t)) * R);
    const float4* lH = (const float4*)(lin + (size_t)(b * 64 + h) * 24);
    const float4* lT = (const float4*)(lin + (size_t)(b * 64 + t) * 24 + 12);
    const float4* blv = (const float4*)bl;

    float4* op = (float4*)(out + (size_t)pair * R);
    #pragma unroll
    for (int q = 0; q < 3; ++q) {
        float4 v = vp[q], a = lH[q], c = lT[q], d = blv[q];
        float4 s;
        s.x = 1.f / (1.f + expf(-(v.x + a.x + c.x + d.x)));
        s.y = 1.f / (1.f + expf(-(v.y + a.y + c.y + d.y)));
        s.z = 1.f / (1.f + expf(-(v.z + a.z + c.z + d.z)));
        s.w = 1.f / (1.f + expf(-(v.w + a.w + c.w + d.w)));
        op[q] = s;
    }
}

// -----------------------------------------------------------------------------
extern "C" void kernel_launch(void* const* d_in, const int* in_sizes, int n_in,
                              void* d_out, int out_size, void* d_ws, size_t ws_size,
                              hipStream_t stream) {
    const float* enc    = (const float*)d_in[0];   // [B,T,D]
    const float* Wl     = (const float*)d_in[1];   // [2D,R]
    const float* bl     = (const float*)d_in[2];   // [R]
    const float* Wb     = (const float*)d_in[3];   // [R,D,D]
    const int*   starts = (const int*)d_in[4];     // [B,S]
    const int*   lens   = (const int*)d_in[5];     // [B,S]
    const int*   ph     = (const int*)d_in[6];     // [B,P]
    const int*   pt     = (const int*)d_in[7];     // [B,P]
    float* out = (float*)d_out;                    // [B,P,R]

    // workspace:
    //   lin f32  [512*24]        =  48 KB
    //   spb bf16 [512*256]       = 256 KB
    //   Wt  bf16 [12*256*256]    = 1.5 MB
    //   V   f32  [8*64*64*12]    = 1.5 MB
    float* lin = (float*)d_ws;
    short* spb = (short*)(lin + (size_t)B * S * 24);
    short* Wt  = spb + (size_t)B * S * D;
    float* V   = (float*)(Wt + (size_t)R * D * D);

    k_prep      <<<B * S + 32 * R, 256, 0, stream>>>(enc, starts, lens, Wl, Wb, spb, lin, Wt);
    k_bilinear_v<<<dim3(B, R),     256, 0, stream>>>(spb, Wt, V);
    k_gather    <<<B * P / 256,    256, 0, stream>>>(V, lin, ph, pt, bl, out);
}

// Round 5
// 87.125 us; speedup vs baseline: 1.3449x; 1.0479x over previous
//
#include <hip/hip_runtime.h>
#include <math.h>

// Problem constants (from reference)
#define B 8
#define T 512
#define D 256
#define S 64
#define P 1024
#define R 12

typedef __attribute__((ext_vector_type(8)))  short bf16x8;   // 8 bf16 = 4 VGPRs
typedef __attribute__((ext_vector_type(16))) float f32x16;   // MFMA 32x32 accum

static __device__ inline short f2bf(float f) {
    union { float f; unsigned u; } v; v.f = f;
    unsigned u = v.u + 0x7fff + ((v.u >> 16) & 1);   // RNE
    return (short)(u >> 16);
}

// -----------------------------------------------------------------------------
// Kernel A (merged): blocks [0,512): ragged span max-pool + per-span linear
// precompute + bf16 span vectors. blocks [512,896): Wb[r][d][e] -> Wt[r][e][d] bf16.
// -----------------------------------------------------------------------------
__global__ __launch_bounds__(256) void k_prep(
    const float* __restrict__ enc, const int* __restrict__ starts,
    const int* __restrict__ lens, const float* __restrict__ Wl,
    const float* __restrict__ Wb,
    short* __restrict__ spb, float* __restrict__ lin, short* __restrict__ Wt)
{
    if (blockIdx.x < B * S) {
        // ---- span max-pool ----
        int bs = blockIdx.x;          // b*S + s
        int b  = bs >> 6;             // S = 64
        int d  = threadIdx.x;
        int st = starts[bs];
        int ln = lens[bs];            // inclusive last offset; ln in [0,11]

        const float* base = enc + ((size_t)(b * T + st)) * D + d;
        float m = base[0];
        // clamped full unroll: independent loads, no serial latency chain
        #pragma unroll
        for (int i = 1; i < 12; ++i) {
            int idx = (i <= ln) ? i : ln;
            m = fmaxf(m, base[(size_t)idx * D]);
        }
        spb[(size_t)bs * D + d] = f2bf(m);

        __shared__ float smem[256];
        smem[d] = m;
        __syncthreads();

        // 24 linear outputs; 4 waves x 6 outputs each, 64-lane shuffle reduce
        int wave = d >> 6, lane = d & 63;
        #pragma unroll
        for (int oo = 0; oo < 6; ++oo) {
            int o = wave * 6 + oo;                 // 0..23
            int r = (o < 12) ? o : (o - 12);
            int rowbase = (o < 12) ? 0 : D;
            float p = 0.f;
            #pragma unroll
            for (int k = 0; k < 4; ++k) {
                int dd = lane + 64 * k;
                p = fmaf(smem[dd], Wl[(size_t)(rowbase + dd) * R + r], p);
            }
            #pragma unroll
            for (int off = 32; off > 0; off >>= 1) p += __shfl_down(p, off, 64);
            if (lane == 0) lin[(size_t)bs * 24 + o] = p;
        }
    } else {
        // ---- Wb transpose + bf16 convert ----
        int bid  = blockIdx.x - B * S;  // 0..383
        int dblk = bid & 31;            // d block (8 rows)
        int r    = bid >> 5;            // 0..11
        int e    = threadIdx.x;         // 0..255

        const float* src = Wb + ((size_t)r * D + dblk * 8) * D + e;
        short v[8];
        #pragma unroll
        for (int j = 0; j < 8; ++j) v[j] = f2bf(src[(size_t)j * D]);

        short* dst = Wt + ((size_t)r * D + e) * D + dblk * 8;
        *(bf16x8*)dst = *(bf16x8*)v;
    }
}

// -----------------------------------------------------------------------------
// Kernel B: fused bilinear + pair gather. Block = (b, r), 4 waves.
// Phase 1: U[s,e] = sum_d spb[b,s,d] * Wt[r,e,d]   (64 x 256, K=256, MFMA)
//          wave w owns e-quarter w: 2x2 tiles of 32x32. U -> LDS as bf16.
// Phase 2: V[s,t] = sum_e U[s,e] * spb[b,t,e]      (64 x 64,  K=256, MFMA)
//          wave w owns tile (w>>1, w&1). A from LDS, B = spb rows (global).
//          V -> LDS (f32). V never touches global.
// Phase 3: each thread handles 4 of the batch's 1024 pairs:
//          out[b,p,r] = sigmoid(V_lds[h*64+t] + linH[r] + linT[12+r] + bl[r])
//          Block (b,r) owns a disjoint r-stripe of out — no races.
// C/D layout (32x32): n = lane&31, m = (reg&3) + 8*(reg>>2) + 4*(lane>>5).
// -----------------------------------------------------------------------------
#define LDSTRIDE 264   // shorts per U row: 256 + 8 pad (row = 528 B, 16B-aligned)
__global__ __launch_bounds__(256) void k_bilinear_gather(
    const short* __restrict__ spb, const short* __restrict__ Wt,
    const float* __restrict__ lin, const int* __restrict__ ph,
    const int* __restrict__ pt, const float* __restrict__ bl,
    float* __restrict__ out)
{
    int b = blockIdx.x;
    int r = blockIdx.y;
    int wave = threadIdx.x >> 6;
    int lane = threadIdx.x & 63;
    int half = lane >> 5;         // k-octet selector
    int mn   = lane & 31;

    __shared__ short ldsU[64 * LDSTRIDE];   // ~33.8 KB
    __shared__ float ldsV[64 * 64];         // 16 KB

    // ---- phase 1: U = spb[b] * Wt[r]^T ----
    {
        int n0 = wave * 64;       // e-quarter
        const short* ap0 = spb + ((size_t)(b * 64 + mn))      * D + half * 8;
        const short* ap1 = ap0 + 32 * D;
        const short* bp0 = Wt + ((size_t)r * D + (n0 + mn))      * D + half * 8;
        const short* bp1 = bp0 + 32 * D;

        f32x16 acc00 = {}, acc01 = {}, acc10 = {}, acc11 = {};
        #pragma unroll
        for (int ks = 0; ks < 16; ++ks) {
            bf16x8 a0 = *(const bf16x8*)(ap0 + ks * 16);
            bf16x8 a1 = *(const bf16x8*)(ap1 + ks * 16);
            bf16x8 b0 = *(const bf16x8*)(bp0 + ks * 16);
            bf16x8 b1 = *(const bf16x8*)(bp1 + ks * 16);
            acc00 = __builtin_amdgcn_mfma_f32_32x32x16_bf16(a0, b0, acc00, 0, 0, 0);
            acc01 = __builtin_amdgcn_mfma_f32_32x32x16_bf16(a0, b1, acc01, 0, 0, 0);
            acc10 = __builtin_amdgcn_mfma_f32_32x32x16_bf16(a1, b0, acc10, 0, 0, 0);
            acc11 = __builtin_amdgcn_mfma_f32_32x32x16_bf16(a1, b1, acc11, 0, 0, 0);
        }

        #pragma unroll
        for (int reg = 0; reg < 16; ++reg) {
            int mrow = (reg & 3) + 8 * (reg >> 2) + 4 * half;
            int e0 = n0 + mn, e1 = n0 + 32 + mn;
            ldsU[(size_t)(mrow)      * LDSTRIDE + e0] = f2bf(acc00[reg]);
            ldsU[(size_t)(mrow)      * LDSTRIDE + e1] = f2bf(acc01[reg]);
            ldsU[(size_t)(mrow + 32) * LDSTRIDE + e0] = f2bf(acc10[reg]);
            ldsU[(size_t)(mrow + 32) * LDSTRIDE + e1] = f2bf(acc11[reg]);
        }
    }
    __syncthreads();

    // ---- phase 2: V = U * spb[b]^T  (to LDS) ----
    {
        int mt = (wave >> 1) * 32;    // s-half
        int nt = (wave & 1) * 32;     // t-half
        const short* ap = ldsU + (size_t)(mt + mn) * LDSTRIDE + half * 8;
        const short* bp = spb + ((size_t)(b * 64 + nt + mn)) * D + half * 8;

        f32x16 acc = {};
        #pragma unroll
        for (int ks = 0; ks < 16; ++ks) {
            bf16x8 a = *(const bf16x8*)(ap + ks * 16);
            bf16x8 bb = *(const bf16x8*)(bp + ks * 16);
            acc = __builtin_amdgcn_mfma_f32_32x32x16_bf16(a, bb, acc, 0, 0, 0);
        }

        #pragma unroll
        for (int reg = 0; reg < 16; ++reg) {
            int s = mt + (reg & 3) + 8 * (reg >> 2) + 4 * half;
            int t = nt + mn;
            ldsV[s * 64 + t] = acc[reg];
        }
    }
    __syncthreads();

    // ---- phase 3: pair gather + sigmoid ----
    {
        float blr = bl[r];
        #pragma unroll
        for (int i = 0; i < 4; ++i) {
            int p = i * 256 + threadIdx.x;
            int h = ph[(size_t)b * P + p];
            int t = pt[(size_t)b * P + p];
            float sc = ldsV[h * 64 + t]
                     + lin[(size_t)(b * 64 + h) * 24 + r]
                     + lin[(size_t)(b * 64 + t) * 24 + 12 + r]
                     + blr;
            out[(size_t)(b * P + p) * R + r] = 1.f / (1.f + expf(-sc));
        }
    }
}

// -----------------------------------------------------------------------------
extern "C" void kernel_launch(void* const* d_in, const int* in_sizes, int n_in,
                              void* d_out, int out_size, void* d_ws, size_t ws_size,
                              hipStream_t stream) {
    const float* enc    = (const float*)d_in[0];   // [B,T,D]
    const float* Wl     = (const float*)d_in[1];   // [2D,R]
    const float* bl     = (const float*)d_in[2];   // [R]
    const float* Wb     = (const float*)d_in[3];   // [R,D,D]
    const int*   starts = (const int*)d_in[4];     // [B,S]
    const int*   lens   = (const int*)d_in[5];     // [B,S]
    const int*   ph     = (const int*)d_in[6];     // [B,P]
    const int*   pt     = (const int*)d_in[7];     // [B,P]
    float* out = (float*)d_out;                    // [B,P,R]

    // workspace:
    //   lin f32  [512*24]        =  48 KB
    //   spb bf16 [512*256]       = 256 KB
    //   Wt  bf16 [12*256*256]    = 1.5 MB
    float* lin = (float*)d_ws;
    short* spb = (short*)(lin + (size_t)B * S * 24);
    short* Wt  = spb + (size_t)B * S * D;

    k_prep           <<<B * S + 32 * R, 256, 0, stream>>>(enc, starts, lens, Wl, Wb, spb, lin, Wt);
    k_bilinear_gather<<<dim3(B, R),     256, 0, stream>>>(spb, Wt, lin, ph, pt, bl, out);
}